// Round 3
// baseline (249.511 us; speedup 1.0000x reference)
//
#include <hip/hip_runtime.h>
#include <math.h>

// LIF recurrence: v_t = v_{t-1}*decay*(1-z_{t-1}) + x_t ; z_t = (v_t > 0.3)
// x [B=128,T=2048,H=128] f32; out [B,T,H] f32 spikes.
//
// R6: combine R3's LDS-fed x (multi-wave DMA BW) with R5's alias-free serial
// loop. Post-mortem R3-R5: limiter was the compute wave's x-feed, not the
// VALU chain. One wave streaming global tops out ~12 GB/s (512 KB -> ~43us);
// LDS-fed x with per-step z ds_write to the SAME buffer alias-fenced every
// read (~100cy/step). Fix: x ring in LDS (DMA-filled), compute does ZERO LDS
// writes (z goes straight to global from an 8-reg rotation), x reads batched
// 8 ahead into registers (compiler emits counted lgkmcnt, nothing fences it).
//
//   256 blocks x 5 waves:
//   wave0  : 64 serial chains. Per 8-step batch: issue next batch's 8
//            ds_read_b32, run dependent chain on current batch (regs only),
//            8 coalesced global_store_dword of z (256 B/inst, fire+forget).
//   wave1-4: DMA producers. 8 x global_load_lds(16B) per tile per wave,
//            3-tile lookahead, counted s_waitcnt vmcnt(16) (never 0 in the
//            steady loop) -> 24 KB/wave in flight across barriers.
//
// Ring (XBUF=4, 128 KB): tile k+3 fills buf (k-1)&3 during iter k; compute's
// ds_reads of that buf all retired before BAR(k-1) (values consumed by the
// chain before the stores, before the barrier). Invariant at BAR(k): tiles
// <= k+1 resident (DMA waited vmcnt(16) after issuing k+3: only k+2,k+3
// outstanding). Tail: k=13 wait vmcnt(8) -> tile14; k=14 wait vmcnt(0).

constexpr int Bdim = 128;
constexpr int Tdim = 2048;
constexpr int Hdim = 128;
constexpr int HW   = 64;          // chains per block
constexpr int U    = 128;         // timesteps per tile (32 KB)
constexpr int XBUF = 4;           // x ring depth (128 KB LDS)
constexpr int NTILE = Tdim / U;   // 16
constexpr int NW   = 5;           // 1 compute + 4 DMA waves
constexpr float VTH = 0.3f;

typedef const __attribute__((address_space(1))) void* gptr_t;
typedef __attribute__((address_space(3))) void* lptr_t;

#define BAR() asm volatile("s_barrier" ::: "memory")

__global__ __launch_bounds__(NW * 64) void lif_kernel(
    const float* __restrict__ x,
    const float* __restrict__ v0,
    const float* __restrict__ z0,
    const float* __restrict__ decay_raw,
    float* __restrict__ out)
{
    __shared__ float xs[XBUF][U][HW];

    const int tid  = threadIdx.x;
    const int wave = tid >> 6;
    const int lane = tid & 63;
    const int blk  = blockIdx.x;          // 0..255
    const int b    = blk >> 1;
    const int h0   = (blk & 1) * HW;

    const float* xbase = x   + (size_t)b * Tdim * Hdim + h0;
    float*       obase = out + (size_t)b * Tdim * Hdim + h0;

    if (wave == 0) {
        // ---- compute wave: x from LDS (read-only!), z -> global direct ----
        const float decay = 1.0f / (1.0f + expf(-decay_raw[h0 + lane]));
        float v = v0[b * Hdim + h0 + lane];
        float z = z0[b * Hdim + h0 + lane];
        float* ol = obase + lane;                        // lane's own channel

        BAR();                                           // tile 0 resident

        for (int k = 0; k < NTILE; ++k) {
            const float (*xt)[HW] = xs[k & 3];
            float xa[8], xb[8], zb[8];
            #pragma unroll
            for (int j = 0; j < 8; ++j) xa[j] = xt[j][lane];

            #pragma unroll
            for (int bt = 0; bt < 16; ++bt) {
                if (bt < 15) {                           // prefetch next batch
                    #pragma unroll
                    for (int j = 0; j < 8; ++j) {
                        const float t = xt[(bt + 1) * 8 + j][lane];
                        if (bt & 1) xa[j] = t; else xb[j] = t;
                    }
                }
                #pragma unroll
                for (int j = 0; j < 8; ++j) {            // 8-step dependent chain
                    const float xv = (bt & 1) ? xb[j] : xa[j];
                    const float vd = v * decay;
                    v = ((z > 0.5f) ? 0.0f : vd) + xv;   // exact: z in {0,1}
                    z = (v > VTH) ? 1.0f : 0.0f;
                    zb[j] = z;
                }
                const size_t t0 = (size_t)k * U + bt * 8;
                #pragma unroll
                for (int j = 0; j < 8; ++j)              // coalesced 256B stores
                    ol[(t0 + j) * Hdim] = zb[j];
            }
            BAR();
        }
    } else {
        // ---- DMA waves 1..4: fill x ring, counted vmcnt, never drain ----
        // inst jj covers tile rows [4jj,4jj+4): lane i -> row 4jj+(i>>4),
        // col (i&15)*4; HW writes lane i at lds_base + i*16 B. Matches.
        const int sub = (lane >> 4) * Hdim + (lane & 15) * 4;

        auto fill = [&](int tile, int buf) {
            const float* g = xbase + (size_t)tile * U * Hdim + sub;
            #pragma unroll
            for (int q = 0; q < 8; ++q) {
                const int jj = (wave - 1) * 8 + q;       // 4 waves x 8 = 32
                __builtin_amdgcn_global_load_lds(
                    (gptr_t)(const void*)(g + (size_t)(4 * jj) * Hdim),
                    (lptr_t)(void*)&xs[buf][4 * jj][0],
                    16, 0, 0);
            }
        };

        fill(0, 0); fill(1, 1); fill(2, 2);              // 24 outstanding
        asm volatile("s_waitcnt vmcnt(16)" ::: "memory"); // tile 0 done
        BAR();

        for (int k = 0; k < NTILE; ++k) {
            if (k + 3 < NTILE) {
                fill(k + 3, (k + 3) & 3);                // 24 outstanding
                asm volatile("s_waitcnt vmcnt(16)" ::: "memory"); // k+1 done
            } else if (k == NTILE - 3) {
                asm volatile("s_waitcnt vmcnt(8)" ::: "memory");  // tile 14 done
            } else if (k == NTILE - 2) {
                asm volatile("s_waitcnt vmcnt(0)" ::: "memory");  // tile 15 done
            }
            BAR();
        }
    }
}

extern "C" void kernel_launch(void* const* d_in, const int* in_sizes, int n_in,
                              void* d_out, int out_size, void* d_ws, size_t ws_size,
                              hipStream_t stream) {
    const float* x         = (const float*)d_in[0];
    const float* v0        = (const float*)d_in[1];
    const float* z0        = (const float*)d_in[2];
    const float* decay_raw = (const float*)d_in[3];
    float* out = (float*)d_out;

    lif_kernel<<<Bdim * Hdim / HW, NW * 64, 0, stream>>>(x, v0, z0, decay_raw, out);
}